// Round 14
// baseline (241.480 us; speedup 1.0000x reference)
//
#include <hip/hip_runtime.h>

// GeodesicShooting on [160^3,3] f32, AoS layout.
// ALL blur passes use the proven blur_x_vec4 shape (15 us measured): one float4
// per thread, 9 independent taps, masked weights, no LDS, no barriers.
//   z/y: taps orthogonal to packing axis -> tap = in4[s + (t-4)*STRIDE4],
//        uniform validity per float4 (rows are float4-aligned: 480 floats/row).
//   x:   in-thread 12-voxel window (taps along packing axis), 2^-6 scale fused.
//   steps: R4 MLP gather + XCD swizzle (~24.5 us, ~95% of traffic floor).
// Identity grid folded analytically: s = idx + 79.5*v.
// Parity: z vel->OUT ; y OUT->WS ; x WS->OUT(scale) ; steps OUT->WS->...->OUT.

constexpr int W = 160, H = 160, D = 160;
constexpr int NVOX = W * H * D;            // 4,096,000
constexpr int NF4  = NVOX * 3 / 4;         // 3,072,000 float4 slots
constexpr int NSTEPS = 6;
constexpr float HSC = 79.5f;               // 0.5*(W-1)

__device__ __forceinline__ int iclamp(int v, int lo, int hi) {
    return v < lo ? lo : (v > hi ? hi : v);
}

// ---- blur along z or y: one float4/thread, 9 orthogonal taps ----
// float4 slot s: row = s/120 (row = (z*H+y)); axis coord = (s/DIV4) % 160.
// DIV4/STRIDE4 = 19200 (z) or 120 (y).
template<int DIV4>
__global__ void blur_f4(const float4* __restrict__ in, float4* __restrict__ out,
                        const float* __restrict__ gk)
{
    int b = blockIdx.x;
    int bs = (b & 7) * 1500 + (b >> 3);     // 12000 blocks, bijective XCD swizzle
    int s = bs * 256 + threadIdx.x;
    int cc = (s / DIV4) % 160;              // coordinate along blur axis

    float kw[9];
#pragma unroll
    for (int t = 0; t < 9; ++t) kw[t] = gk[t];

    // 9 independent float4 loads (clamped addr), masked weights
    float4 win[9];
    float  w[9];
#pragma unroll
    for (int t = 0; t < 9; ++t) {
        int tc = cc + t - 4;
        bool ok = (tc >= 0) && (tc < 160);
        w[t] = ok ? kw[t] : 0.0f;
        int off = ok ? (t - 4) * DIV4 : 0;
        win[t] = in[s + off];
    }

    float a0 = 0.f, a1 = 0.f, a2 = 0.f, a3 = 0.f;
#pragma unroll
    for (int t = 0; t < 9; ++t) {
        a0 = fmaf(w[t], win[t].x, a0);
        a1 = fmaf(w[t], win[t].y, a1);
        a2 = fmaf(w[t], win[t].z, a2);
        a3 = fmaf(w[t], win[t].w, a3);
    }
    out[s] = make_float4(a0, a1, a2, a3);
}

// ---- blur along x (+ 2^-6 scale): 4 voxels/thread, 9 float4 window loads ----
__global__ void blur_x_vec4(const float* __restrict__ in, float* __restrict__ out,
                            const float* __restrict__ gk, float scale)
{
    int tid = blockIdx.x * blockDim.x + threadIdx.x;    // 1,024,000 threads
    if (tid >= NVOX / 4) return;
    int nx4 = W / 4;                                     // 40
    int x0 = (tid % nx4) * 4;
    int row = tid / nx4;                                 // (z*H + y)
    size_t rowBase = (size_t)row * W * 3;

    float kw[9];
#pragma unroll
    for (int t = 0; t < 9; ++t) kw[t] = gk[t];

    long f0 = (long)rowBase + (long)(x0 - 4) * 3;        // may be negative at x0==0
    const long maxF4 = (long)NVOX * 3 - 4;
    float wv[36];
#pragma unroll
    for (int k = 0; k < 9; ++k) {
        long a = f0 + 4 * k;
        a = a < 0 ? 0 : (a > maxF4 ? maxF4 : a);
        float4 v4 = *(const float4*)(in + a);
        wv[4 * k + 0] = v4.x; wv[4 * k + 1] = v4.y;
        wv[4 * k + 2] = v4.z; wv[4 * k + 3] = v4.w;
    }
#pragma unroll
    for (int m = 0; m < 12; ++m) {
        int xi = x0 - 4 + m;
        if (xi < 0 || xi >= W) { wv[3 * m] = 0.f; wv[3 * m + 1] = 0.f; wv[3 * m + 2] = 0.f; }
    }

    float o[12];
#pragma unroll
    for (int j = 0; j < 4; ++j) {
#pragma unroll
        for (int cth = 0; cth < 3; ++cth) {
            float s = 0.f;
#pragma unroll
            for (int t = 0; t < 9; ++t) s = fmaf(kw[t], wv[3 * (j + t) + cth], s);
            o[3 * j + cth] = s * scale;
        }
    }
    float4* q = (float4*)(out + rowBase + (size_t)x0 * 3);
    q[0] = make_float4(o[0], o[1], o[2],  o[3]);
    q[1] = make_float4(o[4], o[5], o[6],  o[7]);
    q[2] = make_float4(o[8], o[9], o[10], o[11]);
}

// ---- one scaling-and-squaring step: out = v + trilerp(v, id + v), AoS ----
__global__ void step_kernel(const float* __restrict__ v, float* __restrict__ out)
{
    int b = blockIdx.x;
    int bs = (b & 7) * 2000 + (b >> 3);                 // bijective XCD swizzle
    int i = bs * blockDim.x + threadIdx.x;
    int x = i % W;
    int t = i / W;
    int y = t % H;
    int z = t / H;

    const float* pv = v + (size_t)i * 3;
    float vx = pv[0], vy = pv[1], vz = pv[2];

    float sx = fmaf(vx, HSC, (float)x);
    float sy = fmaf(vy, HSC, (float)y);
    float sz = fmaf(vz, HSC, (float)z);

    float fx = floorf(sx), fy = floorf(sy), fz = floorf(sz);
    int x0 = (int)fx, y0 = (int)fy, z0 = (int)fz;
    float wx1 = sx - fx, wy1 = sy - fy, wz1 = sz - fz;
    float wx0 = 1.f - wx1, wy0 = 1.f - wy1, wz0 = 1.f - wz1;

    wx0 *= (x0     >= 0 && x0     < W) ? 1.f : 0.f;
    wx1 *= (x0 + 1 >= 0 && x0 + 1 < W) ? 1.f : 0.f;
    wy0 *= (y0     >= 0 && y0     < H) ? 1.f : 0.f;
    wy1 *= (y0 + 1 >= 0 && y0 + 1 < H) ? 1.f : 0.f;
    wz0 *= (z0     >= 0 && z0     < D) ? 1.f : 0.f;
    wz1 *= (z0 + 1 >= 0 && z0 + 1 < D) ? 1.f : 0.f;

    int xc0 = iclamp(x0, 0, W - 1), xc1 = iclamp(x0 + 1, 0, W - 1);
    int yc0 = iclamp(y0, 0, H - 1), yc1 = iclamp(y0 + 1, 0, H - 1);
    int zc0 = iclamp(z0, 0, D - 1), zc1 = iclamp(z0 + 1, 0, D - 1);

    int idx[8];
    idx[0] = (zc0 * H + yc0) * W + xc0;
    idx[1] = (zc0 * H + yc0) * W + xc1;
    idx[2] = (zc0 * H + yc1) * W + xc0;
    idx[3] = (zc0 * H + yc1) * W + xc1;
    idx[4] = (zc1 * H + yc0) * W + xc0;
    idx[5] = (zc1 * H + yc0) * W + xc1;
    idx[6] = (zc1 * H + yc1) * W + xc0;
    idx[7] = (zc1 * H + yc1) * W + xc1;

    float c[8][3];
#pragma unroll
    for (int k = 0; k < 8; ++k) {
        const float* p = v + (size_t)idx[k] * 3;
        c[k][0] = p[0];
        c[k][1] = p[1];
        c[k][2] = p[2];
    }

    float w8[8];
    w8[0] = wz0 * wy0 * wx0;
    w8[1] = wz0 * wy0 * wx1;
    w8[2] = wz0 * wy1 * wx0;
    w8[3] = wz0 * wy1 * wx1;
    w8[4] = wz1 * wy0 * wx0;
    w8[5] = wz1 * wy0 * wx1;
    w8[6] = wz1 * wy1 * wx0;
    w8[7] = wz1 * wy1 * wx1;

    float r0 = vx, r1 = vy, r2 = vz;
#pragma unroll
    for (int k = 0; k < 8; ++k) {
        r0 = fmaf(w8[k], c[k][0], r0);
        r1 = fmaf(w8[k], c[k][1], r1);
        r2 = fmaf(w8[k], c[k][2], r2);
    }

    float* q = out + (size_t)i * 3;
    q[0] = r0;
    q[1] = r1;
    q[2] = r2;
}

extern "C" void kernel_launch(void* const* d_in, const int* in_sizes, int n_in,
                              void* d_out, int out_size, void* d_ws, size_t ws_size,
                              hipStream_t stream)
{
    const float* vel = (const float*)d_in[0];
    // d_in[1] (identity grid) folded analytically
    const float* gk  = (const float*)d_in[2];   // 9 taps

    float* OUT = (float*)d_out;
    float* WS  = (float*)d_ws;                  // one [NVOX,3] f32 buffer

    const int threads = 256;
    const int f4Blocks  = NF4 / threads;                // 12000 (% 8 == 0)
    const int x4Blocks  = (NVOX / 4) / threads;         // 4000
    const int stepBlocks = NVOX / threads;              // 16000
    const float scale = 1.0f / (float)(1 << NSTEPS);    // 2^-6

    // blur: z (vel->OUT), y (OUT->WS), x+scale (WS->OUT)
    blur_f4<19200><<<f4Blocks, threads, 0, stream>>>((const float4*)vel, (float4*)OUT, gk);
    blur_f4<120  ><<<f4Blocks, threads, 0, stream>>>((const float4*)OUT, (float4*)WS, gk);
    blur_x_vec4<<<x4Blocks, threads, 0, stream>>>(WS, OUT, gk, scale);

    // 6 squaring steps: OUT -> WS -> OUT -> WS -> OUT -> WS -> OUT
    step_kernel<<<stepBlocks, threads, 0, stream>>>(OUT, WS);
    step_kernel<<<stepBlocks, threads, 0, stream>>>(WS, OUT);
    step_kernel<<<stepBlocks, threads, 0, stream>>>(OUT, WS);
    step_kernel<<<stepBlocks, threads, 0, stream>>>(WS, OUT);
    step_kernel<<<stepBlocks, threads, 0, stream>>>(OUT, WS);
    step_kernel<<<stepBlocks, threads, 0, stream>>>(WS, OUT);
}

// Round 15
// 234.952 us; speedup vs baseline: 1.0278x; 1.0278x over previous
//
#include <hip/hip_runtime.h>

// GeodesicShooting on [160^3,3] f32, AoS layout.
// z/y blur: 4 consecutive axis-outputs per thread (float4-wide), 12 strided tap
// loads batched BEFORE a sched_barrier(0) so hipcc cannot sink them into the
// FMA loop (the JIT-scheduling that serialized every previous strided-tap blur).
// x blur: contiguous-window vec4 kernel (measured at its 15.6 us BW floor).
// steps: R4 MLP gather + XCD swizzle (~24.5 us, at traffic floor).
// Identity grid folded analytically: s = idx + 79.5*v.
// Parity: z vel->OUT ; y OUT->WS ; x WS->OUT(scale) ; steps OUT->WS->...->OUT.

constexpr int W = 160, H = 160, D = 160;
constexpr int NVOX = W * H * D;            // 4,096,000
constexpr int NF4  = NVOX * 3 / 4;         // 3,072,000 float4 slots
constexpr int NSTEPS = 6;
constexpr float HSC = 79.5f;               // 0.5*(W-1)

__device__ __forceinline__ int iclamp(int v, int lo, int hi) {
    return v < lo ? lo : (v > hi ? hi : v);
}

// ---- blur along z or y: 4 outputs/thread, 12 batched taps, float4-wide ----
// ZAXIS: thread owns column slot c (0..19199), outputs z=a0..a0+3, stride 19200.
// !ZAXIS: thread owns (z, c) with c in-row float4 slot (0..119), outputs
//         y=a0..a0+3, stride 120.
template<bool ZAXIS>
__global__ void blur_f4x4(const float4* __restrict__ in, float4* __restrict__ out,
                          const float* __restrict__ gk)
{
    int b = blockIdx.x;
    int bs = (b & 7) * 375 + (b >> 3);       // 3000 blocks, bijective XCD swizzle
    int u = bs * 256 + threadIdx.x;          // 768,000 threads

    int a0, s0, STRIDE;
    if (ZAXIS) {
        STRIDE = 19200;
        int c = u % 19200;
        int g = u / 19200;                   // 0..39
        a0 = g * 4;
        s0 = a0 * 19200 + c;
    } else {
        STRIDE = 120;
        int c = u % 120;
        int r = u / 120;
        int g = r % 40;
        int z = r / 40;
        a0 = g * 4;
        s0 = z * 19200 + a0 * 120 + c;
    }

    float kw[9];
#pragma unroll
    for (int t = 0; t < 9; ++t) kw[t] = gk[t];

    // batch ALL 12 window loads (clamped addresses); masks applied in weights
    float4 win[12];
    bool okm[12];
#pragma unroll
    for (int m = 0; m < 12; ++m) {
        int ac = a0 - 4 + m;
        bool ok = (ac >= 0) && (ac < 160);
        okm[m] = ok;
        win[m] = in[s0 + (ok ? (m - 4) * STRIDE : 0)];
    }
    __builtin_amdgcn_sched_barrier(0);       // loads may not sink past this

    // 4 outputs; output j uses taps m = j..j+8 with kernel index k = m-j
#pragma unroll
    for (int j = 0; j < 4; ++j) {
        float r0 = 0.f, r1 = 0.f, r2 = 0.f, r3 = 0.f;
#pragma unroll
        for (int k = 0; k < 9; ++k) {
            int m = j + k;
            float w = okm[m] ? kw[k] : 0.0f;
            r0 = fmaf(w, win[m].x, r0);
            r1 = fmaf(w, win[m].y, r1);
            r2 = fmaf(w, win[m].z, r2);
            r3 = fmaf(w, win[m].w, r3);
        }
        out[s0 + j * STRIDE] = make_float4(r0, r1, r2, r3);
    }
}

// ---- blur along x (+ 2^-6 scale): 4 voxels/thread, 9 float4 window loads ----
__global__ void blur_x_vec4(const float* __restrict__ in, float* __restrict__ out,
                            const float* __restrict__ gk, float scale)
{
    int tid = blockIdx.x * blockDim.x + threadIdx.x;    // 1,024,000 threads
    if (tid >= NVOX / 4) return;
    int nx4 = W / 4;                                     // 40
    int x0 = (tid % nx4) * 4;
    int row = tid / nx4;                                 // (z*H + y)
    size_t rowBase = (size_t)row * W * 3;

    float kw[9];
#pragma unroll
    for (int t = 0; t < 9; ++t) kw[t] = gk[t];

    long f0 = (long)rowBase + (long)(x0 - 4) * 3;        // may be negative at x0==0
    const long maxF4 = (long)NVOX * 3 - 4;
    float wv[36];
#pragma unroll
    for (int k = 0; k < 9; ++k) {
        long a = f0 + 4 * k;
        a = a < 0 ? 0 : (a > maxF4 ? maxF4 : a);
        float4 v4 = *(const float4*)(in + a);
        wv[4 * k + 0] = v4.x; wv[4 * k + 1] = v4.y;
        wv[4 * k + 2] = v4.z; wv[4 * k + 3] = v4.w;
    }
#pragma unroll
    for (int m = 0; m < 12; ++m) {
        int xi = x0 - 4 + m;
        if (xi < 0 || xi >= W) { wv[3 * m] = 0.f; wv[3 * m + 1] = 0.f; wv[3 * m + 2] = 0.f; }
    }

    float o[12];
#pragma unroll
    for (int j = 0; j < 4; ++j) {
#pragma unroll
        for (int cth = 0; cth < 3; ++cth) {
            float s = 0.f;
#pragma unroll
            for (int t = 0; t < 9; ++t) s = fmaf(kw[t], wv[3 * (j + t) + cth], s);
            o[3 * j + cth] = s * scale;
        }
    }
    float4* q = (float4*)(out + rowBase + (size_t)x0 * 3);
    q[0] = make_float4(o[0], o[1], o[2],  o[3]);
    q[1] = make_float4(o[4], o[5], o[6],  o[7]);
    q[2] = make_float4(o[8], o[9], o[10], o[11]);
}

// ---- one scaling-and-squaring step: out = v + trilerp(v, id + v), AoS ----
__global__ void step_kernel(const float* __restrict__ v, float* __restrict__ out)
{
    int b = blockIdx.x;
    int bs = (b & 7) * 2000 + (b >> 3);                 // bijective XCD swizzle
    int i = bs * blockDim.x + threadIdx.x;
    int x = i % W;
    int t = i / W;
    int y = t % H;
    int z = t / H;

    const float* pv = v + (size_t)i * 3;
    float vx = pv[0], vy = pv[1], vz = pv[2];

    float sx = fmaf(vx, HSC, (float)x);
    float sy = fmaf(vy, HSC, (float)y);
    float sz = fmaf(vz, HSC, (float)z);

    float fx = floorf(sx), fy = floorf(sy), fz = floorf(sz);
    int x0 = (int)fx, y0 = (int)fy, z0 = (int)fz;
    float wx1 = sx - fx, wy1 = sy - fy, wz1 = sz - fz;
    float wx0 = 1.f - wx1, wy0 = 1.f - wy1, wz0 = 1.f - wz1;

    wx0 *= (x0     >= 0 && x0     < W) ? 1.f : 0.f;
    wx1 *= (x0 + 1 >= 0 && x0 + 1 < W) ? 1.f : 0.f;
    wy0 *= (y0     >= 0 && y0     < H) ? 1.f : 0.f;
    wy1 *= (y0 + 1 >= 0 && y0 + 1 < H) ? 1.f : 0.f;
    wz0 *= (z0     >= 0 && z0     < D) ? 1.f : 0.f;
    wz1 *= (z0 + 1 >= 0 && z0 + 1 < D) ? 1.f : 0.f;

    int xc0 = iclamp(x0, 0, W - 1), xc1 = iclamp(x0 + 1, 0, W - 1);
    int yc0 = iclamp(y0, 0, H - 1), yc1 = iclamp(y0 + 1, 0, H - 1);
    int zc0 = iclamp(z0, 0, D - 1), zc1 = iclamp(z0 + 1, 0, D - 1);

    int idx[8];
    idx[0] = (zc0 * H + yc0) * W + xc0;
    idx[1] = (zc0 * H + yc0) * W + xc1;
    idx[2] = (zc0 * H + yc1) * W + xc0;
    idx[3] = (zc0 * H + yc1) * W + xc1;
    idx[4] = (zc1 * H + yc0) * W + xc0;
    idx[5] = (zc1 * H + yc0) * W + xc1;
    idx[6] = (zc1 * H + yc1) * W + xc0;
    idx[7] = (zc1 * H + yc1) * W + xc1;

    float c[8][3];
#pragma unroll
    for (int k = 0; k < 8; ++k) {
        const float* p = v + (size_t)idx[k] * 3;
        c[k][0] = p[0];
        c[k][1] = p[1];
        c[k][2] = p[2];
    }

    float w8[8];
    w8[0] = wz0 * wy0 * wx0;
    w8[1] = wz0 * wy0 * wx1;
    w8[2] = wz0 * wy1 * wx0;
    w8[3] = wz0 * wy1 * wx1;
    w8[4] = wz1 * wy0 * wx0;
    w8[5] = wz1 * wy0 * wx1;
    w8[6] = wz1 * wy1 * wx0;
    w8[7] = wz1 * wy1 * wx1;

    float r0 = vx, r1 = vy, r2 = vz;
#pragma unroll
    for (int k = 0; k < 8; ++k) {
        r0 = fmaf(w8[k], c[k][0], r0);
        r1 = fmaf(w8[k], c[k][1], r1);
        r2 = fmaf(w8[k], c[k][2], r2);
    }

    float* q = out + (size_t)i * 3;
    q[0] = r0;
    q[1] = r1;
    q[2] = r2;
}

extern "C" void kernel_launch(void* const* d_in, const int* in_sizes, int n_in,
                              void* d_out, int out_size, void* d_ws, size_t ws_size,
                              hipStream_t stream)
{
    const float* vel = (const float*)d_in[0];
    // d_in[1] (identity grid) folded analytically
    const float* gk  = (const float*)d_in[2];   // 9 taps

    float* OUT = (float*)d_out;
    float* WS  = (float*)d_ws;                  // one [NVOX,3] f32 buffer

    const int threads = 256;
    const int f4x4Blocks = (NF4 / 4) / threads;         // 3000 (% 8 == 0)
    const int x4Blocks   = (NVOX / 4) / threads;        // 4000
    const int stepBlocks = NVOX / threads;              // 16000
    const float scale = 1.0f / (float)(1 << NSTEPS);    // 2^-6

    // blur: z (vel->OUT), y (OUT->WS), x+scale (WS->OUT)
    blur_f4x4<true ><<<f4x4Blocks, threads, 0, stream>>>((const float4*)vel, (float4*)OUT, gk);
    blur_f4x4<false><<<f4x4Blocks, threads, 0, stream>>>((const float4*)OUT, (float4*)WS, gk);
    blur_x_vec4<<<x4Blocks, threads, 0, stream>>>(WS, OUT, gk, scale);

    // 6 squaring steps: OUT -> WS -> OUT -> WS -> OUT -> WS -> OUT
    step_kernel<<<stepBlocks, threads, 0, stream>>>(OUT, WS);
    step_kernel<<<stepBlocks, threads, 0, stream>>>(WS, OUT);
    step_kernel<<<stepBlocks, threads, 0, stream>>>(OUT, WS);
    step_kernel<<<stepBlocks, threads, 0, stream>>>(WS, OUT);
    step_kernel<<<stepBlocks, threads, 0, stream>>>(OUT, WS);
    step_kernel<<<stepBlocks, threads, 0, stream>>>(WS, OUT);
}

// Round 16
// 230.779 us; speedup vs baseline: 1.0464x; 1.0181x over previous
//
#include <hip/hip_runtime.h>

// GeodesicShooting on [160^3,3] f32, AoS layout.
// z/y blur: 4 axis-outputs/thread, 12 batched strided taps + sched_barrier
// (R15), with BLOCK ORDER REMAPPED so the blur axis is the inner dispatch
// dimension: consecutive blocks share tap planes/rows -> reuse window ~688 KB
// fits the 4 MB XCD L2 (R15's plane-sweep order had 14 MB reuse distance ->
// all taps fell to L3, 9x logical traffic at L3 BW = the stubborn ~36-45 us).
// x blur: contiguous-window vec4 kernel (at its 15.6 us BW floor).
// steps: R4 MLP gather + XCD swizzle (~24.5 us, at traffic floor).
// Identity grid folded analytically: s = idx + 79.5*v.
// Parity: z vel->OUT ; y OUT->WS ; x WS->OUT(scale) ; steps OUT->WS->...->OUT.

constexpr int W = 160, H = 160, D = 160;
constexpr int NVOX = W * H * D;            // 4,096,000
constexpr int NF4  = NVOX * 3 / 4;         // 3,072,000 float4 slots
constexpr int NSTEPS = 6;
constexpr float HSC = 79.5f;               // 0.5*(W-1)

__device__ __forceinline__ int iclamp(int v, int lo, int hi) {
    return v < lo ? lo : (v > hi ? hi : v);
}

// ---- blur along z or y: 4 outputs/thread, 12 batched taps, axis-inner order ----
// ZAXIS: bs -> (cb, g): c = cb*256+tid (plane slot), outputs z = 4g..4g+3.
//        Consecutive bs = consecutive g, same c-chunk -> tap planes L2-resident.
// !ZAXIS: bs -> (uc, yg): u = uc*256+tid indexes (z,c) pairs (z=u/120, c=u%120),
//        outputs y = 4yg..4yg+3. Consecutive bs share tap rows.
template<bool ZAXIS>
__global__ void blur_f4x4(const float4* __restrict__ in, float4* __restrict__ out,
                          const float* __restrict__ gk)
{
    int b = blockIdx.x;
    int bs = (b & 7) * 375 + (b >> 3);       // 3000 blocks, bijective XCD swizzle
    int chunk = bs / 40;                      // 0..74 column chunk
    int g     = bs % 40;                      // axis group (inner!)
    int a0 = g * 4;

    int s0, STRIDE;
    if (ZAXIS) {
        STRIDE = 19200;
        int c = chunk * 256 + threadIdx.x;    // plane float4 slot 0..19199
        s0 = a0 * 19200 + c;
    } else {
        STRIDE = 120;
        int u = chunk * 256 + threadIdx.x;    // (z,c) pair 0..19199
        int z = u / 120;
        int c = u % 120;
        s0 = z * 19200 + a0 * 120 + c;
    }

    float kw[9];
#pragma unroll
    for (int t = 0; t < 9; ++t) kw[t] = gk[t];

    // batch ALL 12 window loads (clamped addresses); masks applied in weights
    float4 win[12];
    bool okm[12];
#pragma unroll
    for (int m = 0; m < 12; ++m) {
        int ac = a0 - 4 + m;
        bool ok = (ac >= 0) && (ac < 160);
        okm[m] = ok;
        win[m] = in[s0 + (ok ? (m - 4) * STRIDE : 0)];
    }
    __builtin_amdgcn_sched_barrier(0);       // loads may not sink past this

    // 4 outputs; output j uses taps m = j..j+8 with kernel index k = m-j
#pragma unroll
    for (int j = 0; j < 4; ++j) {
        float r0 = 0.f, r1 = 0.f, r2 = 0.f, r3 = 0.f;
#pragma unroll
        for (int k = 0; k < 9; ++k) {
            int m = j + k;
            float w = okm[m] ? kw[k] : 0.0f;
            r0 = fmaf(w, win[m].x, r0);
            r1 = fmaf(w, win[m].y, r1);
            r2 = fmaf(w, win[m].z, r2);
            r3 = fmaf(w, win[m].w, r3);
        }
        out[s0 + j * STRIDE] = make_float4(r0, r1, r2, r3);
    }
}

// ---- blur along x (+ 2^-6 scale): 4 voxels/thread, 9 float4 window loads ----
__global__ void blur_x_vec4(const float* __restrict__ in, float* __restrict__ out,
                            const float* __restrict__ gk, float scale)
{
    int tid = blockIdx.x * blockDim.x + threadIdx.x;    // 1,024,000 threads
    if (tid >= NVOX / 4) return;
    int nx4 = W / 4;                                     // 40
    int x0 = (tid % nx4) * 4;
    int row = tid / nx4;                                 // (z*H + y)
    size_t rowBase = (size_t)row * W * 3;

    float kw[9];
#pragma unroll
    for (int t = 0; t < 9; ++t) kw[t] = gk[t];

    long f0 = (long)rowBase + (long)(x0 - 4) * 3;        // may be negative at x0==0
    const long maxF4 = (long)NVOX * 3 - 4;
    float wv[36];
#pragma unroll
    for (int k = 0; k < 9; ++k) {
        long a = f0 + 4 * k;
        a = a < 0 ? 0 : (a > maxF4 ? maxF4 : a);
        float4 v4 = *(const float4*)(in + a);
        wv[4 * k + 0] = v4.x; wv[4 * k + 1] = v4.y;
        wv[4 * k + 2] = v4.z; wv[4 * k + 3] = v4.w;
    }
#pragma unroll
    for (int m = 0; m < 12; ++m) {
        int xi = x0 - 4 + m;
        if (xi < 0 || xi >= W) { wv[3 * m] = 0.f; wv[3 * m + 1] = 0.f; wv[3 * m + 2] = 0.f; }
    }

    float o[12];
#pragma unroll
    for (int j = 0; j < 4; ++j) {
#pragma unroll
        for (int cth = 0; cth < 3; ++cth) {
            float s = 0.f;
#pragma unroll
            for (int t = 0; t < 9; ++t) s = fmaf(kw[t], wv[3 * (j + t) + cth], s);
            o[3 * j + cth] = s * scale;
        }
    }
    float4* q = (float4*)(out + rowBase + (size_t)x0 * 3);
    q[0] = make_float4(o[0], o[1], o[2],  o[3]);
    q[1] = make_float4(o[4], o[5], o[6],  o[7]);
    q[2] = make_float4(o[8], o[9], o[10], o[11]);
}

// ---- one scaling-and-squaring step: out = v + trilerp(v, id + v), AoS ----
__global__ void step_kernel(const float* __restrict__ v, float* __restrict__ out)
{
    int b = blockIdx.x;
    int bs = (b & 7) * 2000 + (b >> 3);                 // bijective XCD swizzle
    int i = bs * blockDim.x + threadIdx.x;
    int x = i % W;
    int t = i / W;
    int y = t % H;
    int z = t / H;

    const float* pv = v + (size_t)i * 3;
    float vx = pv[0], vy = pv[1], vz = pv[2];

    float sx = fmaf(vx, HSC, (float)x);
    float sy = fmaf(vy, HSC, (float)y);
    float sz = fmaf(vz, HSC, (float)z);

    float fx = floorf(sx), fy = floorf(sy), fz = floorf(sz);
    int x0 = (int)fx, y0 = (int)fy, z0 = (int)fz;
    float wx1 = sx - fx, wy1 = sy - fy, wz1 = sz - fz;
    float wx0 = 1.f - wx1, wy0 = 1.f - wy1, wz0 = 1.f - wz1;

    wx0 *= (x0     >= 0 && x0     < W) ? 1.f : 0.f;
    wx1 *= (x0 + 1 >= 0 && x0 + 1 < W) ? 1.f : 0.f;
    wy0 *= (y0     >= 0 && y0     < H) ? 1.f : 0.f;
    wy1 *= (y0 + 1 >= 0 && y0 + 1 < H) ? 1.f : 0.f;
    wz0 *= (z0     >= 0 && z0     < D) ? 1.f : 0.f;
    wz1 *= (z0 + 1 >= 0 && z0 + 1 < D) ? 1.f : 0.f;

    int xc0 = iclamp(x0, 0, W - 1), xc1 = iclamp(x0 + 1, 0, W - 1);
    int yc0 = iclamp(y0, 0, H - 1), yc1 = iclamp(y0 + 1, 0, H - 1);
    int zc0 = iclamp(z0, 0, D - 1), zc1 = iclamp(z0 + 1, 0, D - 1);

    int idx[8];
    idx[0] = (zc0 * H + yc0) * W + xc0;
    idx[1] = (zc0 * H + yc0) * W + xc1;
    idx[2] = (zc0 * H + yc1) * W + xc0;
    idx[3] = (zc0 * H + yc1) * W + xc1;
    idx[4] = (zc1 * H + yc0) * W + xc0;
    idx[5] = (zc1 * H + yc0) * W + xc1;
    idx[6] = (zc1 * H + yc1) * W + xc0;
    idx[7] = (zc1 * H + yc1) * W + xc1;

    float c[8][3];
#pragma unroll
    for (int k = 0; k < 8; ++k) {
        const float* p = v + (size_t)idx[k] * 3;
        c[k][0] = p[0];
        c[k][1] = p[1];
        c[k][2] = p[2];
    }

    float w8[8];
    w8[0] = wz0 * wy0 * wx0;
    w8[1] = wz0 * wy0 * wx1;
    w8[2] = wz0 * wy1 * wx0;
    w8[3] = wz0 * wy1 * wx1;
    w8[4] = wz1 * wy0 * wx0;
    w8[5] = wz1 * wy0 * wx1;
    w8[6] = wz1 * wy1 * wx0;
    w8[7] = wz1 * wy1 * wx1;

    float r0 = vx, r1 = vy, r2 = vz;
#pragma unroll
    for (int k = 0; k < 8; ++k) {
        r0 = fmaf(w8[k], c[k][0], r0);
        r1 = fmaf(w8[k], c[k][1], r1);
        r2 = fmaf(w8[k], c[k][2], r2);
    }

    float* q = out + (size_t)i * 3;
    q[0] = r0;
    q[1] = r1;
    q[2] = r2;
}

extern "C" void kernel_launch(void* const* d_in, const int* in_sizes, int n_in,
                              void* d_out, int out_size, void* d_ws, size_t ws_size,
                              hipStream_t stream)
{
    const float* vel = (const float*)d_in[0];
    // d_in[1] (identity grid) folded analytically
    const float* gk  = (const float*)d_in[2];   // 9 taps

    float* OUT = (float*)d_out;
    float* WS  = (float*)d_ws;                  // one [NVOX,3] f32 buffer

    const int threads = 256;
    const int f4x4Blocks = (NF4 / 4) / threads;         // 3000 (% 8 == 0)
    const int x4Blocks   = (NVOX / 4) / threads;        // 4000
    const int stepBlocks = NVOX / threads;              // 16000
    const float scale = 1.0f / (float)(1 << NSTEPS);    // 2^-6

    // blur: z (vel->OUT), y (OUT->WS), x+scale (WS->OUT)
    blur_f4x4<true ><<<f4x4Blocks, threads, 0, stream>>>((const float4*)vel, (float4*)OUT, gk);
    blur_f4x4<false><<<f4x4Blocks, threads, 0, stream>>>((const float4*)OUT, (float4*)WS, gk);
    blur_x_vec4<<<x4Blocks, threads, 0, stream>>>(WS, OUT, gk, scale);

    // 6 squaring steps: OUT -> WS -> OUT -> WS -> OUT -> WS -> OUT
    step_kernel<<<stepBlocks, threads, 0, stream>>>(OUT, WS);
    step_kernel<<<stepBlocks, threads, 0, stream>>>(WS, OUT);
    step_kernel<<<stepBlocks, threads, 0, stream>>>(OUT, WS);
    step_kernel<<<stepBlocks, threads, 0, stream>>>(WS, OUT);
    step_kernel<<<stepBlocks, threads, 0, stream>>>(OUT, WS);
    step_kernel<<<stepBlocks, threads, 0, stream>>>(WS, OUT);
}